// Round 6
// baseline (362.566 us; speedup 1.0000x reference)
//
#include <hip/hip_runtime.h>
#include <stdint.h>

#define N_EDGES 500000
#define N_NODES 100000

typedef __attribute__((ext_vector_type(8))) short short8;
typedef __attribute__((ext_vector_type(4))) float floatx4;

// RNE (used only in one-time weight prep)
__device__ __forceinline__ uint16_t f2bf(float f) {
  union { float f; uint32_t u; } cv; cv.f = f;
  uint32_t u = cv.u;
  return (uint16_t)((u + 0x7FFFu + ((u >> 16) & 1u)) >> 16);
}
// truncating pack of two f32 -> bf16x2, single v_perm_b32
__device__ __forceinline__ uint32_t pk2bf(float lo, float hi) {
  return __builtin_amdgcn_perm(__float_as_uint(hi), __float_as_uint(lo), 0x07060302u);
}
__device__ __forceinline__ uint16_t bftrunc(float f) {
  return (uint16_t)(__float_as_uint(f) >> 16);
}
__device__ __forceinline__ float bf2f_lo(uint32_t u) {
  return __uint_as_float(u << 16);
}
__device__ __forceinline__ float bf2f_hi(uint32_t u) {
  return __uint_as_float(u & 0xFFFF0000u);
}
__device__ __forceinline__ float lrelu(float v) { return fmaxf(v, 0.001f * v); }

// ============ prep0: weights -> MFMA-fragment order (bf16) + BE0 + pos copy ============
// fragment blob: frag[ks][nt][lane][j], element = W[k][n], k = ks*32+(lane>>4)*8+j,
// n = nt*16+(lane&15); a wave's B-frag (ks,nt) is one coalesced 1024B load.
__global__ void prep0_kernel(const float* __restrict__ W0, const float* __restrict__ b0,
                             const float* __restrict__ W1, const float* __restrict__ W2,
                             const float* __restrict__ bemb,
                             uint16_t* __restrict__ w0ab, uint16_t* __restrict__ w0c,
                             uint16_t* __restrict__ w1f, uint16_t* __restrict__ w2f,
                             float* __restrict__ be0f,
                             const float* __restrict__ pos, float* __restrict__ out, int npos) {
  int id = blockIdx.x * 256 + threadIdx.x;
  if (id < 32768) {                       // w0ab: ks(4) x ntt(16) x lane(64) x j(8)
    int f = id;
    int j = f & 7, lane = (f >> 3) & 63, ntt = (f >> 9) & 15, ks = f >> 13;
    int k = ks * 32 + (lane >> 4) * 8 + j;
    int row = (ntt < 8) ? k : (128 + k);            // ntt<8 -> P_a, else P_b
    int col = (ntt & 7) * 16 + (lane & 15);
    w0ab[f] = f2bf(W0[row * 128 + col]);
  } else if (id < 40960) {                // w0c: smear block, W0 rows 320..383, ks(2)
    int f = id - 32768;
    int j = f & 7, lane = (f >> 3) & 63, nt = (f >> 9) & 7, ks = f >> 12;
    int k = ks * 32 + (lane >> 4) * 8 + j;
    w0c[f] = f2bf(W0[(320 + k) * 128 + nt * 16 + (lane & 15)]);
  } else if (id < 57344) {                // w1f
    int f = id - 40960;
    int j = f & 7, lane = (f >> 3) & 63, nt = (f >> 9) & 7, ks = f >> 12;
    int k = ks * 32 + (lane >> 4) * 8 + j;
    w1f[f] = f2bf(W1[k * 128 + nt * 16 + (lane & 15)]);
  } else if (id < 73728) {                // w2f
    int f = id - 57344;
    int j = f & 7, lane = (f >> 3) & 63, nt = (f >> 9) & 7, ks = f >> 12;
    int k = ks * 32 + (lane >> 4) * 8 + j;
    w2f[f] = f2bf(W2[k * 128 + nt * 16 + (lane & 15)]);
  } else if (id < 74240) {                // BE0[t][n] = bond_emb[t] @ W0[256:320] + b0 (f32)
    int t = id - 73728; int ty = t >> 7, n = t & 127;
    float s = b0[n];
    for (int kk = 0; kk < 64; ++kk) s += bemb[ty * 64 + kk] * W0[(256 + kk) * 128 + n];
    be0f[t] = s;
  } else if (id - 74240 < npos) {         // pos -> out
    out[id - 74240] = pos[id - 74240];
  }
}

// ============ prep_p: P_a = nemb @ W0[0:128], P_b = nemb @ W0[128:256] (bf16) ============
// waves_per_eu pinned (3,3): LDS caps blocks anyway; give the scheduler the VGPR
// budget so the b[16] prefetch stays materialized (R5: launch_bounds min alone
// let the scheduler compress to 64-VGPR/8-wave target and serialize loads).
__global__ __attribute__((amdgpu_flat_work_group_size(256, 256), amdgpu_waves_per_eu(3, 3)))
void prep_p_kernel(const float* __restrict__ nemb, const uint16_t* __restrict__ w0ab,
                   uint16_t* __restrict__ Pa, uint16_t* __restrict__ Pb) {
  __shared__ __align__(16) uint16_t aLds[4 * 16 * 136];   // per-wave 16x136 bf16
  const int tid = threadIdx.x;
  const int lane = tid & 63;
  const int wave = tid >> 6;
  const int n15 = lane & 15;
  const int quad = lane >> 4;
  uint16_t* myA = aLds + wave * (16 * 136);
  const int base = blockIdx.x * 64 + wave * 16;

  {
    const int le = lane >> 2, sub = lane & 3;
    int r = base + le; if (r >= N_NODES) r = N_NODES - 1;
    const float4* src = (const float4*)(nemb + (size_t)r * 128);
#pragma unroll
    for (int g = 0; g < 4; ++g) {
      float4 a = src[sub * 8 + g * 2], b = src[sub * 8 + g * 2 + 1];
      uint4 pk;
      pk.x = pk2bf(a.x, a.y); pk.y = pk2bf(a.z, a.w);
      pk.z = pk2bf(b.x, b.y); pk.w = pk2bf(b.z, b.w);
      *(uint4*)(myA + le * 136 + sub * 32 + g * 8) = pk;
    }
  }

  floatx4 acc[16];
#pragma unroll
  for (int t = 0; t < 16; ++t) acc[t] = (floatx4){0.f, 0.f, 0.f, 0.f};
  const short8* wfv = (const short8*)w0ab + lane;
#pragma unroll
  for (int ks = 0; ks < 4; ++ks) {
    short8 a = *(const short8*)(myA + n15 * 136 + ks * 32 + quad * 8);
    short8 b[16];
#pragma unroll
    for (int ntt = 0; ntt < 16; ++ntt) b[ntt] = wfv[(ks * 16 + ntt) * 64];
#pragma unroll
    for (int ntt = 0; ntt < 16; ++ntt)
      acc[ntt] = __builtin_amdgcn_mfma_f32_16x16x32_bf16(a, b[ntt], acc[ntt], 0, 0, 0);
  }

  // write out via LDS transpose, two passes: P_a then P_b
#pragma unroll
  for (int p = 0; p < 2; ++p) {
#pragma unroll
    for (int nt = 0; nt < 8; ++nt)
#pragma unroll
      for (int r = 0; r < 4; ++r)
        myA[(quad * 4 + r) * 136 + nt * 16 + n15] = bftrunc(acc[p * 8 + nt][r]);
    const int le = lane >> 2, sub = lane & 3;
    int row = base + le;
    if (row < N_NODES) {
      uint16_t* dst = (p == 0 ? Pa : Pb) + (size_t)row * 128;
#pragma unroll
      for (int g = 0; g < 4; ++g)
        *(uint4*)(dst + sub * 32 + g * 8) =
            *(const uint4*)(myA + le * 136 + sub * 32 + g * 8);
    }
  }
}

// B-frags from global (fragment-ordered, L2-hot) with register double-buffering:
// 8 loads in flight while 8 MFMAs execute. A-frags preloaded (LDS, wave-private).
template <int NKS>
__device__ __forceinline__ void gemm_fw(const uint16_t* __restrict__ wf,
                                        const uint16_t* aRow, int lane, floatx4* acc) {
  const short8* wfv = (const short8*)wf + lane;
  short8 a[NKS];
#pragma unroll
  for (int ks = 0; ks < NKS; ++ks) a[ks] = *(const short8*)(aRow + ks * 32);
  short8 b0[8], b1[8];
#pragma unroll
  for (int nt = 0; nt < 8; ++nt) b0[nt] = wfv[nt * 64];
#pragma unroll
  for (int ks = 0; ks < NKS; ++ks) {
    const short8* cur = (ks & 1) ? b1 : b0;
    short8* nxt = (ks & 1) ? b0 : b1;
    if (ks + 1 < NKS) {
#pragma unroll
      for (int nt = 0; nt < 8; ++nt) nxt[nt] = wfv[((ks + 1) * 8 + nt) * 64];
    }
#pragma unroll
    for (int nt = 0; nt < 8; ++nt)
      acc[nt] = __builtin_amdgcn_mfma_f32_16x16x32_bf16(a[ks], cur[nt], acc[nt], 0, 0, 0);
  }
}

// ============ main: 64 edges/block, 4 waves, 16 edges/wave, zero barriers ============
// LDS (44KB) caps at 3 blocks/CU = 3 waves/EU; pin waves_per_eu=(3,3) so the
// register allocator gets the full ~168-VGPR budget for load prefetching.
__global__ __attribute__((amdgpu_flat_work_group_size(256, 256), amdgpu_waves_per_eu(3, 3)))
void bond_mlp_kernel(const float* __restrict__ x,
                     const int* __restrict__ bidx, const int* __restrict__ btyp,
                     const uint16_t* __restrict__ Pa, const uint16_t* __restrict__ Pb,
                     const uint16_t* __restrict__ w0c, const uint16_t* __restrict__ w1f,
                     const uint16_t* __restrict__ w2f, const float* __restrict__ be0f,
                     const float* __restrict__ b1, const float* __restrict__ ln1w,
                     const float* __restrict__ ln1b,
                     const float* __restrict__ b2, const float* __restrict__ ln2w,
                     const float* __restrict__ ln2b,
                     const float* __restrict__ Wo, const float* __restrict__ bo,
                     float* __restrict__ out) {
  // per-wave region: h0pre f32 16x130 (aliased later as hA bf16 16x136) + smearA 16x72
  __shared__ __align__(16) uint16_t wlds[4 * 5312];
  __shared__ float u_lds[64][3];
  __shared__ int ij_lds[64][2];
  __shared__ int type_lds[64];

  const int tid = threadIdx.x;
  const int lane = tid & 63;
  const int wave = tid >> 6;
  const int n15 = lane & 15;
  const int quad = lane >> 4;

  uint16_t* base16 = wlds + wave * 5312;
  float* h0pre = (float*)base16;              // 16 rows stride 130 f32
  uint16_t* hA = base16;                      // alias: 16 rows stride 136 bf16
  uint16_t* smearA = base16 + 4160;           // 16 rows stride 72 bf16

  // ---------------- phase 1: gather P_a[i]+P_b[j]+BE0[t] -> h0pre(f32); smear -> smearA ----------------
  {
    const int le = lane >> 2, sub = lane & 3;   // 4 lanes per edge
    const int lrow = le;
    const int ge = blockIdx.x * 64 + wave * 16 + le;
    const bool valid = ge < N_EDGES;
    int vi = 0, vj = 0, bt = 0;
    if (valid) { vi = bidx[2 * ge]; vj = bidx[2 * ge + 1]; bt = btyp[ge]; }
    float dx, dy, dz;
    if (valid) {
      dx = x[3 * vi]     - x[3 * vj];
      dy = x[3 * vi + 1] - x[3 * vj + 1];
      dz = x[3 * vi + 2] - x[3 * vj + 2];
    } else { dx = 1.0f; dy = 0.0f; dz = 0.0f; }
    float dist = sqrtf(dx * dx + dy * dy + dz * dz);
    float rinv = 1.0f / dist;
    if (sub == 0) {
      int gr = wave * 16 + lrow;
      u_lds[gr][0] = dx * rinv; u_lds[gr][1] = dy * rinv; u_lds[gr][2] = dz * rinv;
      ij_lds[gr][0] = vi; ij_lds[gr][1] = vj; type_lds[gr] = bt;
    }
    const uint4* pa = (const uint4*)(Pa + (size_t)vi * 128);
    const uint4* pb = (const uint4*)(Pb + (size_t)vj * 128);
    const float4* bbp = (const float4*)(be0f + bt * 128);
#pragma unroll
    for (int g = 0; g < 4; ++g) {
      uint4 av = pa[sub * 4 + g];
      uint4 bv = pb[sub * 4 + g];
      float4 e0 = bbp[sub * 8 + g * 2], e1 = bbp[sub * 8 + g * 2 + 1];
      float4 s0, s1;
      s0.x = bf2f_lo(av.x) + bf2f_lo(bv.x) + e0.x;
      s0.y = bf2f_hi(av.x) + bf2f_hi(bv.x) + e0.y;
      s0.z = bf2f_lo(av.y) + bf2f_lo(bv.y) + e0.z;
      s0.w = bf2f_hi(av.y) + bf2f_hi(bv.y) + e0.w;
      s1.x = bf2f_lo(av.z) + bf2f_lo(bv.z) + e1.x;
      s1.y = bf2f_hi(av.z) + bf2f_hi(bv.z) + e1.y;
      s1.z = bf2f_lo(av.w) + bf2f_lo(bv.w) + e1.z;
      s1.w = bf2f_hi(av.w) + bf2f_hi(bv.w) + e1.w;
      *(float4*)(h0pre + lrow * 130 + sub * 32 + g * 8) = s0;
      *(float4*)(h0pre + lrow * 130 + sub * 32 + g * 8 + 4) = s1;
    }
    // smear -> smearA (bf16, A-layout rows)
    const float delta = 20.0f / 62.0f;
    const float coeff = -0.5f / (delta * delta);
    float sv[16]; float ssum = 0.0f;
#pragma unroll
    for (int t = 0; t < 16; ++t) {
      int kk = sub * 16 + t;
      float v;
      if (kk < 63) { float d = dist - (float)kk * delta; v = __expf(coeff * d * d); }
      else v = (dist >= 20.0f) ? 1.0f : 0.0f;
      sv[t] = v; ssum += v;
    }
    ssum += __shfl_xor(ssum, 1);
    ssum += __shfl_xor(ssum, 2);
    float sinv = 1.0f / ssum;
#pragma unroll
    for (int g = 0; g < 2; ++g) {
      uint4 pk;
      pk.x = pk2bf(sv[g*8+0]*sinv, sv[g*8+1]*sinv);
      pk.y = pk2bf(sv[g*8+2]*sinv, sv[g*8+3]*sinv);
      pk.z = pk2bf(sv[g*8+4]*sinv, sv[g*8+5]*sinv);
      pk.w = pk2bf(sv[g*8+6]*sinv, sv[g*8+7]*sinv);
      *(uint4*)(smearA + lrow * 72 + sub * 16 + g * 8) = pk;
    }
  }
  // no __syncthreads: all LDS traffic wave-private; per-wave LDS pipe is in-order

  floatx4 acc[8];
#pragma unroll
  for (int nt = 0; nt < 8; ++nt)
#pragma unroll
    for (int r = 0; r < 4; ++r)
      acc[nt][r] = h0pre[(quad * 4 + r) * 130 + nt * 16 + n15];

  // L0c: smear @ W0c (K=64)
  gemm_fw<2>(w0c, smearA + n15 * 72 + quad * 8, lane, acc);

  // epilogue 0: lrelu -> hA (overwrites h0pre AFTER init reads; same wave => ordered)
#pragma unroll
  for (int nt = 0; nt < 8; ++nt)
#pragma unroll
    for (int r = 0; r < 4; ++r)
      hA[(quad * 4 + r) * 136 + nt * 16 + n15] = bftrunc(lrelu(acc[nt][r]));

  // L1
#pragma unroll
  for (int nt = 0; nt < 8; ++nt) acc[nt] = (floatx4){0.f, 0.f, 0.f, 0.f};
  gemm_fw<4>(w1f, hA + n15 * 136 + quad * 8, lane, acc);

  // epilogue 1: +b1, LN, lrelu -> hA
  {
    float bv[8], wv[8], bb2[8];
#pragma unroll
    for (int nt = 0; nt < 8; ++nt) {
      int col = nt * 16 + n15;
      bv[nt] = b1[col]; wv[nt] = ln1w[col]; bb2[nt] = ln1b[col];
    }
    float s[4] = {0,0,0,0}, q[4] = {0,0,0,0};
#pragma unroll
    for (int nt = 0; nt < 8; ++nt)
#pragma unroll
      for (int r = 0; r < 4; ++r) { float v = acc[nt][r] + bv[nt]; s[r] += v; q[r] += v * v; }
#pragma unroll
    for (int m = 1; m <= 8; m <<= 1)
#pragma unroll
      for (int r = 0; r < 4; ++r) { s[r] += __shfl_xor(s[r], m); q[r] += __shfl_xor(q[r], m); }
    float mean[4], rstd[4];
#pragma unroll
    for (int r = 0; r < 4; ++r) {
      mean[r] = s[r] * (1.0f / 128.0f);
      float var = q[r] * (1.0f / 128.0f) - mean[r] * mean[r];
      rstd[r] = rsqrtf(var + 1e-5f);
    }
#pragma unroll
    for (int nt = 0; nt < 8; ++nt)
#pragma unroll
      for (int r = 0; r < 4; ++r) {
        float v = acc[nt][r] + bv[nt];
        float vn = (v - mean[r]) * rstd[r] * wv[nt] + bb2[nt];
        hA[(quad * 4 + r) * 136 + nt * 16 + n15] = bftrunc(lrelu(vn));
      }
  }

  // L2
#pragma unroll
  for (int nt = 0; nt < 8; ++nt) acc[nt] = (floatx4){0.f, 0.f, 0.f, 0.f};
  gemm_fw<4>(w2f, hA + n15 * 136 + quad * 8, lane, acc);

  // epilogue 2: +b2, LN, lrelu, force = h@Wo + bo, scatter atomics
  {
    float bv[8], wv[8], bb2[8], wo0[8], wo1[8];
#pragma unroll
    for (int nt = 0; nt < 8; ++nt) {
      int col = nt * 16 + n15;
      bv[nt] = b2[col]; wv[nt] = ln2w[col]; bb2[nt] = ln2b[col];
      wo0[nt] = Wo[2 * col]; wo1[nt] = Wo[2 * col + 1];
    }
    float s[4] = {0,0,0,0}, q[4] = {0,0,0,0};
#pragma unroll
    for (int nt = 0; nt < 8; ++nt)
#pragma unroll
      for (int r = 0; r < 4; ++r) { float v = acc[nt][r] + bv[nt]; s[r] += v; q[r] += v * v; }
#pragma unroll
    for (int m = 1; m <= 8; m <<= 1)
#pragma unroll
      for (int r = 0; r < 4; ++r) { s[r] += __shfl_xor(s[r], m); q[r] += __shfl_xor(q[r], m); }
    float mean[4], rstd[4];
#pragma unroll
    for (int r = 0; r < 4; ++r) {
      mean[r] = s[r] * (1.0f / 128.0f);
      float var = q[r] * (1.0f / 128.0f) - mean[r] * mean[r];
      rstd[r] = rsqrtf(var + 1e-5f);
    }
    float f0[4] = {0,0,0,0}, f1[4] = {0,0,0,0};
#pragma unroll
    for (int nt = 0; nt < 8; ++nt)
#pragma unroll
      for (int r = 0; r < 4; ++r) {
        float v = acc[nt][r] + bv[nt];
        float vn = lrelu((v - mean[r]) * rstd[r] * wv[nt] + bb2[nt]);
        f0[r] += vn * wo0[nt];
        f1[r] += vn * wo1[nt];
      }
#pragma unroll
    for (int m = 1; m <= 8; m <<= 1)
#pragma unroll
      for (int r = 0; r < 4; ++r) { f0[r] += __shfl_xor(f0[r], m); f1[r] += __shfl_xor(f1[r], m); }

    if (n15 < 4) {
      int gr = wave * 16 + quad * 4 + n15;
      int ge2 = blockIdx.x * 64 + gr;
      if (ge2 < N_EDGES) {
        float F0 = (n15 == 0) ? f0[0] : (n15 == 1) ? f0[1] : (n15 == 2) ? f0[2] : f0[3];
        float F1 = (n15 == 0) ? f1[0] : (n15 == 1) ? f1[1] : (n15 == 2) ? f1[2] : f1[3];
        F0 += bo[0]; F1 += bo[1];
        float ux = u_lds[gr][0], uy = u_lds[gr][1], uz = u_lds[gr][2];
        int ii = ij_lds[gr][0], jj = ij_lds[gr][1];
        float c0 = 0.5f * F0;          // STEP * force0, along +u
        float c1 = -0.5f * F1;         // STEP * force1, along -u
        atomicAdd(out + 3 * ii,     c0 * ux);
        atomicAdd(out + 3 * ii + 1, c0 * uy);
        atomicAdd(out + 3 * ii + 2, c0 * uz);
        atomicAdd(out + 3 * jj,     c1 * ux);
        atomicAdd(out + 3 * jj + 1, c1 * uy);
        atomicAdd(out + 3 * jj + 2, c1 * uz);
      }
    }
  }
}

extern "C" void kernel_launch(void* const* d_in, const int* in_sizes, int n_in,
                              void* d_out, int out_size, void* d_ws, size_t ws_size,
                              hipStream_t stream) {
  const float* x    = (const float*)d_in[0];
  const float* pos  = (const float*)d_in[1];
  const float* nemb = (const float*)d_in[2];
  const int*   bidx = (const int*)d_in[3];
  const int*   btyp = (const int*)d_in[4];
  const float* bemb = (const float*)d_in[5];
  const float* W0   = (const float*)d_in[6];
  const float* b0   = (const float*)d_in[7];
  const float* W1   = (const float*)d_in[8];
  const float* b1   = (const float*)d_in[9];
  const float* ln1w = (const float*)d_in[10];
  const float* ln1b = (const float*)d_in[11];
  const float* W2   = (const float*)d_in[12];
  const float* b2   = (const float*)d_in[13];
  const float* ln2w = (const float*)d_in[14];
  const float* ln2b = (const float*)d_in[15];
  const float* Wo   = (const float*)d_in[16];
  const float* bo   = (const float*)d_in[17];
  float* out = (float*)d_out;

  // workspace: frag weights (144KB) + be0 (2KB) + P_a/P_b (51.2MB)
  uint16_t* w0ab = (uint16_t*)d_ws;                 // 32768 bf16
  uint16_t* w0c  = w0ab + 32768;                    // 8192
  uint16_t* w1f  = w0c + 8192;                      // 16384
  uint16_t* w2f  = w1f + 16384;                     // 16384
  float*    be0f = (float*)(w2f + 16384);           // 512 f32
  uint16_t* Pa   = (uint16_t*)(be0f + 512);         // N_NODES*128 bf16
  uint16_t* Pb   = Pa + (size_t)N_NODES * 128;      // N_NODES*128 bf16

  prep0_kernel<<<(74240 + out_size + 255) / 256, 256, 0, stream>>>(
      W0, b0, W1, W2, bemb, w0ab, w0c, w1f, w2f, be0f, pos, out, out_size);
  prep_p_kernel<<<(N_NODES + 63) / 64, 256, 0, stream>>>(nemb, w0ab, Pa, Pb);
  bond_mlp_kernel<<<(N_EDGES + 63) / 64, 256, 0, stream>>>(
      x, bidx, btyp, Pa, Pb, w0c, w1f, w2f, be0f,
      b1, ln1w, ln1b, b2, ln2w, ln2b, Wo, bo, out);
}

// Round 7
// 353.723 us; speedup vs baseline: 1.0250x; 1.0250x over previous
//
#include <hip/hip_runtime.h>
#include <stdint.h>

#define N_EDGES 500000
#define N_NODES 100000
#define PREP_NG 2   // node-groups per wave in prep_p (B-frags register-resident across groups)

typedef __attribute__((ext_vector_type(8))) short short8;
typedef __attribute__((ext_vector_type(4))) float floatx4;

// RNE (used only in one-time weight prep)
__device__ __forceinline__ uint16_t f2bf(float f) {
  union { float f; uint32_t u; } cv; cv.f = f;
  uint32_t u = cv.u;
  return (uint16_t)((u + 0x7FFFu + ((u >> 16) & 1u)) >> 16);
}
// truncating pack of two f32 -> bf16x2, single v_perm_b32
__device__ __forceinline__ uint32_t pk2bf(float lo, float hi) {
  return __builtin_amdgcn_perm(__float_as_uint(hi), __float_as_uint(lo), 0x07060302u);
}
__device__ __forceinline__ uint16_t bftrunc(float f) {
  return (uint16_t)(__float_as_uint(f) >> 16);
}
__device__ __forceinline__ float bfup(uint16_t h) {
  return __uint_as_float(((uint32_t)h) << 16);
}
__device__ __forceinline__ float bf2f_lo(uint32_t u) {
  return __uint_as_float(u << 16);
}
__device__ __forceinline__ float bf2f_hi(uint32_t u) {
  return __uint_as_float(u & 0xFFFF0000u);
}
__device__ __forceinline__ float lrelu(float v) { return fmaxf(v, 0.001f * v); }

// ============ prep0: weights -> MFMA-fragment order (bf16) + BE0 + pos copy ============
// fragment blob: frag[ks][nt][lane][j], element = W[k][n], k = ks*32+(lane>>4)*8+j,
// n = nt*16+(lane&15); a wave's B-frag (ks,nt) is one coalesced 1024B load.
__global__ void prep0_kernel(const float* __restrict__ W0, const float* __restrict__ b0,
                             const float* __restrict__ W1, const float* __restrict__ W2,
                             const float* __restrict__ bemb,
                             uint16_t* __restrict__ w0ab, uint16_t* __restrict__ w0c,
                             uint16_t* __restrict__ w1f, uint16_t* __restrict__ w2f,
                             float* __restrict__ be0f,
                             const float* __restrict__ pos, float* __restrict__ out, int npos) {
  int id = blockIdx.x * 256 + threadIdx.x;
  if (id < 32768) {                       // w0ab: ks(4) x ntt(16) x lane(64) x j(8)
    int f = id;
    int j = f & 7, lane = (f >> 3) & 63, ntt = (f >> 9) & 15, ks = f >> 13;
    int k = ks * 32 + (lane >> 4) * 8 + j;
    int row = (ntt < 8) ? k : (128 + k);            // ntt<8 -> P_a cols, else P_b cols
    int col = (ntt & 7) * 16 + (lane & 15);
    w0ab[f] = f2bf(W0[row * 128 + col]);
  } else if (id < 40960) {                // w0c: smear block, W0 rows 320..383, ks(2)
    int f = id - 32768;
    int j = f & 7, lane = (f >> 3) & 63, nt = (f >> 9) & 7, ks = f >> 12;
    int k = ks * 32 + (lane >> 4) * 8 + j;
    w0c[f] = f2bf(W0[(320 + k) * 128 + nt * 16 + (lane & 15)]);
  } else if (id < 57344) {                // w1f
    int f = id - 40960;
    int j = f & 7, lane = (f >> 3) & 63, nt = (f >> 9) & 7, ks = f >> 12;
    int k = ks * 32 + (lane >> 4) * 8 + j;
    w1f[f] = f2bf(W1[k * 128 + nt * 16 + (lane & 15)]);
  } else if (id < 73728) {                // w2f
    int f = id - 57344;
    int j = f & 7, lane = (f >> 3) & 63, nt = (f >> 9) & 7, ks = f >> 12;
    int k = ks * 32 + (lane >> 4) * 8 + j;
    w2f[f] = f2bf(W2[k * 128 + nt * 16 + (lane & 15)]);
  } else if (id < 74240) {                // BE0[t][n] = bond_emb[t] @ W0[256:320] + b0 (f32)
    int t = id - 73728; int ty = t >> 7, n = t & 127;
    float s = b0[n];
    for (int kk = 0; kk < 64; ++kk) s += bemb[ty * 64 + kk] * W0[(256 + kk) * 128 + n];
    be0f[t] = s;
  } else if (id - 74240 < npos) {         // pos -> out
    out[id - 74240] = pos[id - 74240];
  }
}

// ============ prep_p: P_a = nemb @ W0[0:128], P_b = nemb @ W0[128:256] (bf16) ============
// Column-quarter split: for each quarter q (4 ntt), load its 16 B-frags ONCE into
// registers (64 VGPR) and reuse across PREP_NG node-groups -> B-residency is
// structurally required, not scheduler-optional. Outputs stored directly from
// C-layout (scalar stores, fire-and-forget).
__global__ __attribute__((amdgpu_flat_work_group_size(256, 256), amdgpu_waves_per_eu(1, 4)))
void prep_p_kernel(const float* __restrict__ nemb, const uint16_t* __restrict__ w0ab,
                   uint16_t* __restrict__ Pa, uint16_t* __restrict__ Pb) {
  __shared__ __align__(16) uint16_t aLds[4 * PREP_NG * 16 * 136];  // per-wave NGx16x136
  const int tid = threadIdx.x;
  const int lane = tid & 63;
  const int wave = tid >> 6;
  const int n15 = lane & 15;
  const int quad = lane >> 4;
  uint16_t* myA = aLds + wave * (PREP_NG * 16 * 136);
  const int base = blockIdx.x * (64 * PREP_NG) + wave * (16 * PREP_NG);

  // stage A rows for all NG groups (fp32 -> bf16), 4 lanes per row
  {
    const int le = lane >> 2, sub = lane & 3;
#pragma unroll
    for (int it = 0; it < PREP_NG; ++it) {
      int r = base + it * 16 + le; if (r >= N_NODES) r = N_NODES - 1;
      const float4* src = (const float4*)(nemb + (size_t)r * 128);
#pragma unroll
      for (int g = 0; g < 4; ++g) {
        float4 a = src[sub * 8 + g * 2], b = src[sub * 8 + g * 2 + 1];
        uint4 pk;
        pk.x = pk2bf(a.x, a.y); pk.y = pk2bf(a.z, a.w);
        pk.z = pk2bf(b.x, b.y); pk.w = pk2bf(b.z, b.w);
        *(uint4*)(myA + (it * 16 + le) * 136 + sub * 32 + g * 8) = pk;
      }
    }
  }
  // wave-private LDS, in-order pipe: no barrier needed

  const short8* wfv = (const short8*)w0ab + lane;
#pragma unroll
  for (int q = 0; q < 4; ++q) {            // quarter q covers ntt = q*4 .. q*4+3
    short8 bfr[16];
#pragma unroll
    for (int ks = 0; ks < 4; ++ks)
#pragma unroll
      for (int nq = 0; nq < 4; ++nq)
        bfr[ks * 4 + nq] = wfv[(ks * 16 + q * 4 + nq) * 64];
#pragma unroll
    for (int it = 0; it < PREP_NG; ++it) {
      floatx4 acc[4];
#pragma unroll
      for (int nq = 0; nq < 4; ++nq) acc[nq] = (floatx4){0.f, 0.f, 0.f, 0.f};
#pragma unroll
      for (int ks = 0; ks < 4; ++ks) {
        short8 a = *(const short8*)(myA + (it * 16 + n15) * 136 + ks * 32 + quad * 8);
#pragma unroll
        for (int nq = 0; nq < 4; ++nq)
          acc[nq] = __builtin_amdgcn_mfma_f32_16x16x32_bf16(a, bfr[ks * 4 + nq], acc[nq], 0, 0, 0);
      }
      // direct C-layout store: row = base+it*16+quad*4+r, col = (q*4+nq)*16+n15
      uint16_t* dst = (q < 2) ? Pa : Pb;
      int cbase = ((q & 1) * 4) * 16 + n15;          // within Pa/Pb: cols 0..127
#pragma unroll
      for (int nq = 0; nq < 4; ++nq) {
        int c = cbase + nq * 16;
#pragma unroll
        for (int r = 0; r < 4; ++r) {
          int row = base + it * 16 + quad * 4 + r;
          if (row < N_NODES) dst[(size_t)row * 128 + c] = bftrunc(acc[nq][r]);
        }
      }
    }
  }
}

// B-frags from global (fragment-ordered, L2-hot)
template <int NKS>
__device__ __forceinline__ void gemm_fw(const uint16_t* __restrict__ wf,
                                        const uint16_t* aRow, int lane, floatx4* acc) {
  const short8* wfv = (const short8*)wf + lane;
  short8 a[NKS];
#pragma unroll
  for (int ks = 0; ks < NKS; ++ks) a[ks] = *(const short8*)(aRow + ks * 32);
#pragma unroll
  for (int ks = 0; ks < NKS; ++ks) {
#pragma unroll
    for (int nt = 0; nt < 8; ++nt) {
      short8 b = wfv[(ks * 8 + nt) * 64];
      acc[nt] = __builtin_amdgcn_mfma_f32_16x16x32_bf16(a[ks], b, acc[nt], 0, 0, 0);
    }
  }
}

// ============ main: 64 edges/block, 4 waves, 16 edges/wave, zero barriers ============
// LDS diet (bf16 h-sum): ~27.5 KB/block -> 5 blocks/CU (20 waves) for latency hiding.
__global__ __attribute__((amdgpu_flat_work_group_size(256, 256)))
void bond_mlp_kernel(const float* __restrict__ x,
                     const int* __restrict__ bidx, const int* __restrict__ btyp,
                     const uint16_t* __restrict__ Pa, const uint16_t* __restrict__ Pb,
                     const uint16_t* __restrict__ w0c, const uint16_t* __restrict__ w1f,
                     const uint16_t* __restrict__ w2f, const float* __restrict__ be0f,
                     const float* __restrict__ b1, const float* __restrict__ ln1w,
                     const float* __restrict__ ln1b,
                     const float* __restrict__ b2, const float* __restrict__ ln2w,
                     const float* __restrict__ ln2b,
                     const float* __restrict__ Wo, const float* __restrict__ bo,
                     float* __restrict__ out) {
  // per-wave region: hA bf16 16x136 (2176 el) + smearA bf16 16x72 (1152 el) = 3328 el
  __shared__ __align__(16) uint16_t wlds[4 * 3328];   // 26624 B
  __shared__ float u_lds[64][3];
  __shared__ int ij_lds[64][2];
  __shared__ int type_lds[64];

  const int tid = threadIdx.x;
  const int lane = tid & 63;
  const int wave = tid >> 6;
  const int n15 = lane & 15;
  const int quad = lane >> 4;

  uint16_t* hA = wlds + wave * 3328;          // 16 rows stride 136 bf16
  uint16_t* smearA = hA + 2176;               // 16 rows stride 72 bf16

  // ---------------- phase 1: gather bf16(P_a[i]+P_b[j]+BE0[t]) -> hA; smear -> smearA ----------------
  {
    const int le = lane >> 2, sub = lane & 3;   // 4 lanes per edge
    const int lrow = le;
    const int ge = blockIdx.x * 64 + wave * 16 + le;
    const bool valid = ge < N_EDGES;
    int vi = 0, vj = 0, bt = 0;
    if (valid) { vi = bidx[2 * ge]; vj = bidx[2 * ge + 1]; bt = btyp[ge]; }
    float dx, dy, dz;
    if (valid) {
      dx = x[3 * vi]     - x[3 * vj];
      dy = x[3 * vi + 1] - x[3 * vj + 1];
      dz = x[3 * vi + 2] - x[3 * vj + 2];
    } else { dx = 1.0f; dy = 0.0f; dz = 0.0f; }
    float dist = sqrtf(dx * dx + dy * dy + dz * dz);
    float rinv = 1.0f / dist;
    if (sub == 0) {
      int gr = wave * 16 + lrow;
      u_lds[gr][0] = dx * rinv; u_lds[gr][1] = dy * rinv; u_lds[gr][2] = dz * rinv;
      ij_lds[gr][0] = vi; ij_lds[gr][1] = vj; type_lds[gr] = bt;
    }
    const uint4* pa = (const uint4*)(Pa + (size_t)vi * 128);
    const uint4* pb = (const uint4*)(Pb + (size_t)vj * 128);
    const float4* bbp = (const float4*)(be0f + bt * 128);
#pragma unroll
    for (int g = 0; g < 4; ++g) {
      uint4 av = pa[sub * 4 + g];
      uint4 bv = pb[sub * 4 + g];
      float4 e0 = bbp[sub * 8 + g * 2], e1 = bbp[sub * 8 + g * 2 + 1];
      uint4 pk;
      pk.x = pk2bf(bf2f_lo(av.x) + bf2f_lo(bv.x) + e0.x,
                   bf2f_hi(av.x) + bf2f_hi(bv.x) + e0.y);
      pk.y = pk2bf(bf2f_lo(av.y) + bf2f_lo(bv.y) + e0.z,
                   bf2f_hi(av.y) + bf2f_hi(bv.y) + e0.w);
      pk.z = pk2bf(bf2f_lo(av.z) + bf2f_lo(bv.z) + e1.x,
                   bf2f_hi(av.z) + bf2f_hi(bv.z) + e1.y);
      pk.w = pk2bf(bf2f_lo(av.w) + bf2f_lo(bv.w) + e1.z,
                   bf2f_hi(av.w) + bf2f_hi(bv.w) + e1.w);
      *(uint4*)(hA + lrow * 136 + sub * 32 + g * 8) = pk;
    }
    // smear -> smearA (bf16, A-layout rows)
    const float delta = 20.0f / 62.0f;
    const float coeff = -0.5f / (delta * delta);
    float sv[16]; float ssum = 0.0f;
#pragma unroll
    for (int t = 0; t < 16; ++t) {
      int kk = sub * 16 + t;
      float v;
      if (kk < 63) { float d = dist - (float)kk * delta; v = __expf(coeff * d * d); }
      else v = (dist >= 20.0f) ? 1.0f : 0.0f;
      sv[t] = v; ssum += v;
    }
    ssum += __shfl_xor(ssum, 1);
    ssum += __shfl_xor(ssum, 2);
    float sinv = 1.0f / ssum;
#pragma unroll
    for (int g = 0; g < 2; ++g) {
      uint4 pk;
      pk.x = pk2bf(sv[g*8+0]*sinv, sv[g*8+1]*sinv);
      pk.y = pk2bf(sv[g*8+2]*sinv, sv[g*8+3]*sinv);
      pk.z = pk2bf(sv[g*8+4]*sinv, sv[g*8+5]*sinv);
      pk.w = pk2bf(sv[g*8+6]*sinv, sv[g*8+7]*sinv);
      *(uint4*)(smearA + lrow * 72 + sub * 16 + g * 8) = pk;
    }
  }
  // no __syncthreads: all LDS traffic wave-private; per-wave LDS pipe is in-order

  floatx4 acc[8];
#pragma unroll
  for (int nt = 0; nt < 8; ++nt)
#pragma unroll
    for (int r = 0; r < 4; ++r)
      acc[nt][r] = bfup(hA[(quad * 4 + r) * 136 + nt * 16 + n15]);

  // L0c: smear @ W0c (K=64)
  gemm_fw<2>(w0c, smearA + n15 * 72 + quad * 8, lane, acc);

  // epilogue 0: lrelu -> hA (overwrites cells already consumed by acc init; same wave => ordered)
#pragma unroll
  for (int nt = 0; nt < 8; ++nt)
#pragma unroll
    for (int r = 0; r < 4; ++r)
      hA[(quad * 4 + r) * 136 + nt * 16 + n15] = bftrunc(lrelu(acc[nt][r]));

  // L1
#pragma unroll
  for (int nt = 0; nt < 8; ++nt) acc[nt] = (floatx4){0.f, 0.f, 0.f, 0.f};
  gemm_fw<4>(w1f, hA + n15 * 136 + quad * 8, lane, acc);

  // epilogue 1: +b1, LN, lrelu -> hA
  {
    float bv[8], wv[8], bb2[8];
#pragma unroll
    for (int nt = 0; nt < 8; ++nt) {
      int col = nt * 16 + n15;
      bv[nt] = b1[col]; wv[nt] = ln1w[col]; bb2[nt] = ln1b[col];
    }
    float s[4] = {0,0,0,0}, q[4] = {0,0,0,0};
#pragma unroll
    for (int nt = 0; nt < 8; ++nt)
#pragma unroll
      for (int r = 0; r < 4; ++r) { float v = acc[nt][r] + bv[nt]; s[r] += v; q[r] += v * v; }
#pragma unroll
    for (int m = 1; m <= 8; m <<= 1)
#pragma unroll
      for (int r = 0; r < 4; ++r) { s[r] += __shfl_xor(s[r], m); q[r] += __shfl_xor(q[r], m); }
    float mean[4], rstd[4];
#pragma unroll
    for (int r = 0; r < 4; ++r) {
      mean[r] = s[r] * (1.0f / 128.0f);
      float var = q[r] * (1.0f / 128.0f) - mean[r] * mean[r];
      rstd[r] = rsqrtf(var + 1e-5f);
    }
#pragma unroll
    for (int nt = 0; nt < 8; ++nt)
#pragma unroll
      for (int r = 0; r < 4; ++r) {
        float v = acc[nt][r] + bv[nt];
        float vn = (v - mean[r]) * rstd[r] * wv[nt] + bb2[nt];
        hA[(quad * 4 + r) * 136 + nt * 16 + n15] = bftrunc(lrelu(vn));
      }
  }

  // L2
#pragma unroll
  for (int nt = 0; nt < 8; ++nt) acc[nt] = (floatx4){0.f, 0.f, 0.f, 0.f};
  gemm_fw<4>(w2f, hA + n15 * 136 + quad * 8, lane, acc);

  // epilogue 2: +b2, LN, lrelu, force = h@Wo + bo, scatter atomics
  {
    float bv[8], wv[8], bb2[8], wo0[8], wo1[8];
#pragma unroll
    for (int nt = 0; nt < 8; ++nt) {
      int col = nt * 16 + n15;
      bv[nt] = b2[col]; wv[nt] = ln2w[col]; bb2[nt] = ln2b[col];
      wo0[nt] = Wo[2 * col]; wo1[nt] = Wo[2 * col + 1];
    }
    float s[4] = {0,0,0,0}, q[4] = {0,0,0,0};
#pragma unroll
    for (int nt = 0; nt < 8; ++nt)
#pragma unroll
      for (int r = 0; r < 4; ++r) { float v = acc[nt][r] + bv[nt]; s[r] += v; q[r] += v * v; }
#pragma unroll
    for (int m = 1; m <= 8; m <<= 1)
#pragma unroll
      for (int r = 0; r < 4; ++r) { s[r] += __shfl_xor(s[r], m); q[r] += __shfl_xor(q[r], m); }
    float mean[4], rstd[4];
#pragma unroll
    for (int r = 0; r < 4; ++r) {
      mean[r] = s[r] * (1.0f / 128.0f);
      float var = q[r] * (1.0f / 128.0f) - mean[r] * mean[r];
      rstd[r] = rsqrtf(var + 1e-5f);
    }
    float f0[4] = {0,0,0,0}, f1[4] = {0,0,0,0};
#pragma unroll
    for (int nt = 0; nt < 8; ++nt)
#pragma unroll
      for (int r = 0; r < 4; ++r) {
        float v = acc[nt][r] + bv[nt];
        float vn = lrelu((v - mean[r]) * rstd[r] * wv[nt] + bb2[nt]);
        f0[r] += vn * wo0[nt];
        f1[r] += vn * wo1[nt];
      }
#pragma unroll
    for (int m = 1; m <= 8; m <<= 1)
#pragma unroll
      for (int r = 0; r < 4; ++r) { f0[r] += __shfl_xor(f0[r], m); f1[r] += __shfl_xor(f1[r], m); }

    if (n15 < 4) {
      int gr = wave * 16 + quad * 4 + n15;
      int ge2 = blockIdx.x * 64 + gr;
      if (ge2 < N_EDGES) {
        float F0 = (n15 == 0) ? f0[0] : (n15 == 1) ? f0[1] : (n15 == 2) ? f0[2] : f0[3];
        float F1 = (n15 == 0) ? f1[0] : (n15 == 1) ? f1[1] : (n15 == 2) ? f1[2] : f1[3];
        F0 += bo[0]; F1 += bo[1];
        float ux = u_lds[gr][0], uy = u_lds[gr][1], uz = u_lds[gr][2];
        int ii = ij_lds[gr][0], jj = ij_lds[gr][1];
        float c0 = 0.5f * F0;          // STEP * force0, along +u
        float c1 = -0.5f * F1;         // STEP * force1, along -u
        atomicAdd(out + 3 * ii,     c0 * ux);
        atomicAdd(out + 3 * ii + 1, c0 * uy);
        atomicAdd(out + 3 * ii + 2, c0 * uz);
        atomicAdd(out + 3 * jj,     c1 * ux);
        atomicAdd(out + 3 * jj + 1, c1 * uy);
        atomicAdd(out + 3 * jj + 2, c1 * uz);
      }
    }
  }
}

extern "C" void kernel_launch(void* const* d_in, const int* in_sizes, int n_in,
                              void* d_out, int out_size, void* d_ws, size_t ws_size,
                              hipStream_t stream) {
  const float* x    = (const float*)d_in[0];
  const float* pos  = (const float*)d_in[1];
  const float* nemb = (const float*)d_in[2];
  const int*   bidx = (const int*)d_in[3];
  const int*   btyp = (const int*)d_in[4];
  const float* bemb = (const float*)d_in[5];
  const float* W0   = (const float*)d_in[6];
  const float* b0   = (const float*)d_in[7];
  const float* W1   = (const float*)d_in[8];
  const float* b1   = (const float*)d_in[9];
  const float* ln1w = (const float*)d_in[10];
  const float* ln1b = (const float*)d_in[11];
  const float* W2   = (const float*)d_in[12];
  const float* b2   = (const float*)d_in[13];
  const float* ln2w = (const float*)d_in[14];
  const float* ln2b = (const float*)d_in[15];
  const float* Wo   = (const float*)d_in[16];
  const float* bo   = (const float*)d_in[17];
  float* out = (float*)d_out;

  // workspace: frag weights (144KB) + be0 (2KB) + P_a/P_b (51.2MB)
  uint16_t* w0ab = (uint16_t*)d_ws;                 // 32768 bf16
  uint16_t* w0c  = w0ab + 32768;                    // 8192
  uint16_t* w1f  = w0c + 8192;                      // 16384
  uint16_t* w2f  = w1f + 16384;                     // 16384
  float*    be0f = (float*)(w2f + 16384);           // 512 f32
  uint16_t* Pa   = (uint16_t*)(be0f + 512);         // N_NODES*128 bf16
  uint16_t* Pb   = Pa + (size_t)N_NODES * 128;      // N_NODES*128 bf16

  prep0_kernel<<<(74240 + out_size + 255) / 256, 256, 0, stream>>>(
      W0, b0, W1, W2, bemb, w0ab, w0c, w1f, w2f, be0f, pos, out, out_size);
  prep_p_kernel<<<(N_NODES + 64 * PREP_NG - 1) / (64 * PREP_NG), 256, 0, stream>>>(
      nemb, w0ab, Pa, Pb);
  bond_mlp_kernel<<<(N_EDGES + 63) / 64, 256, 0, stream>>>(
      x, bidx, btyp, Pa, Pb, w0c, w1f, w2f, be0f,
      b1, ln1w, ln1b, b2, ln2w, ln2b, Wo, bo, out);
}